// Round 2
// baseline (919.717 us; speedup 1.0000x reference)
//
#include <hip/hip_runtime.h>
#include <cstdint>
#include <cstddef>

// ---------------------------------------------------------------------------
// SlotAttention on MI355X.
//  (1) prepack: bf16 weight images in MFMA B-fragment order; slot_init copy.
//  (2) gemm_kv: x=LN(inputs); [k|v] = x @ [k_w/16 | v_w] via bf16 MFMA.
//      R4: 64-token blocks, 512 thr (8 waves), acc[4][4], concurrent K+V
//      scatter. R5: FUSED iter-0 QK+softmax: K image is already in LDS in
//      attn's pi-permuted layout; waves 0-3 compute dots vs q (from fuse0),
//      softmax over slots, and store packed bf16 P B-frags (4 MB). This is
//      bit-identical to attn's pb path (which also rounds P to bf16).
//  (3) attn_pv (iter 0): PV-only streaming kernel — no kfr read, no QK
//      MFMAs, no serial softmax/transform. rs recomputed from bf16 P.
//  (4) attn (iters 1,2): unchanged structure + s_setprio around MFMA.
//  (5) fuse: reduce partials, renorm, GRU, LN, MLP, residual, pack next q.
//      Launch order: prepack -> fuse0 -> gemm_kv -> attn_pv -> fuse1 ->
//      (attn -> fuse1) x2.
// ---------------------------------------------------------------------------

typedef __attribute__((ext_vector_type(8))) short short8;
typedef __attribute__((ext_vector_type(4))) float f32x4;
typedef __attribute__((ext_vector_type(4))) unsigned short us4;
typedef __attribute__((ext_vector_type(8))) unsigned short us8;

#define DEV static __device__ __forceinline__

DEV unsigned short f2bf(float f) {
  union { float f; unsigned int u; } v; v.f = f;
  unsigned int r = v.u + 0x7FFFu + ((v.u >> 16) & 1u);
  return (unsigned short)(r >> 16);
}

DEV float bf2f(unsigned short h) {
  union { unsigned int u; float f; } v; v.u = ((unsigned int)h) << 16;
  return v.f;
}

DEV f32x4 mfma16(short8 a, short8 b, f32x4 c) {
  return __builtin_amdgcn_mfma_f32_16x16x32_bf16(a, b, c, 0, 0, 0);
}

// ---------------- workspace layout (bytes) ----------------
constexpr size_t O_KF   = 0;                                  // k frags: [64][256 tb][8 dc][64 chunk(pi)][8] bf16
constexpr size_t SZ_KF  = (size_t)64*256*8*64*8*2;            // 128 MB
constexpr size_t O_VF   = O_KF + SZ_KF;                       // v frags: [64][128 c32][16 dt][64][8] bf16
constexpr size_t SZ_VF  = (size_t)64*128*16*64*8*2;           // 128 MB
constexpr size_t O_ACC  = O_VF + SZ_VF;                       // [64][16 blk][8][256] f32 (8.4 MB used)
constexpr size_t SZ_ACC = (size_t)64*32*8*256*4;              // 16 MB reserved
constexpr size_t O_P    = O_ACC + (size_t)12*1024*1024;       // packed P: [64][128 c32][32][8] bf16 = 4 MB
constexpr size_t O_SUM  = O_ACC + SZ_ACC;                     // [64][16][8] f32
constexpr size_t SZ_SUM = (size_t)64*32*8*4;
constexpr size_t O_SL   = O_SUM + SZ_SUM;                     // slots [64][8][256] f32
constexpr size_t SZ_SL  = (size_t)64*8*256*4;
constexpr size_t O_QF   = O_SL + SZ_SL;                       // q frags [64][8 dc][64][8] bf16
constexpr size_t SZ_QF  = (size_t)64*8*64*8*2;
constexpr size_t O_WKV  = O_QF + SZ_QF;                       // [32 ct][8 dc][64][8]
constexpr size_t SZ_WKV = (size_t)32*8*64*8*2;
constexpr size_t O_WQ   = O_WKV + SZ_WKV;                     // [16][8][64][8]
constexpr size_t SZ_WQ  = (size_t)16*8*64*8*2;
constexpr size_t O_WGRU = O_WQ + SZ_WQ;                       // [96][8][64][8] (wi:0-47, wh:48-95)
constexpr size_t SZ_WGRU= (size_t)96*8*64*8*2;
constexpr size_t O_WM1  = O_WGRU + SZ_WGRU;                   // [32][8][64][8]
constexpr size_t SZ_WM1 = (size_t)32*8*64*8*2;
constexpr size_t O_WM2  = O_WM1 + SZ_WM1;                     // [16][16][64][8]
constexpr size_t SZ_WM2 = (size_t)16*16*64*8*2;
constexpr size_t WS_NEED= O_WM2 + SZ_WM2;                     // ~275 MB (unchanged)

// ---------------------------------------------------------------------------
// prepack: weight fragment images + slots init. 544 blocks x 256.
// B-frag convention: lane L holds W[k = dc*32 + (L>>4)*8 + j][col = ct*16 + (L&15)]
// ---------------------------------------------------------------------------
__global__ void prepack(
    const float* __restrict__ kw, const float* __restrict__ qw,
    const float* __restrict__ vw, const float* __restrict__ wi,
    const float* __restrict__ wh, const float* __restrict__ w1,
    const float* __restrict__ w2, const float* __restrict__ slot_init,
    unsigned short* __restrict__ wkv, unsigned short* __restrict__ wq_,
    unsigned short* __restrict__ wgru, unsigned short* __restrict__ wm1,
    unsigned short* __restrict__ wm2, float* __restrict__ slots)
{
  int idx = blockIdx.x * 256 + threadIdx.x;
  if (idx < 16384) {                                    // kv: [32][8][64]
    int ct = idx >> 9, dc = (idx >> 6) & 7, L = idx & 63;
    int col = ct*16 + (L & 15), k0 = dc*32 + ((L>>4)*8);
    if (col < 256) {
      for (int j = 0; j < 8; ++j) wkv[idx*8+j] = f2bf(kw[(size_t)(k0+j)*256 + col] * 0.0625f);
    } else {
      int c = col - 256;
      for (int j = 0; j < 8; ++j) wkv[idx*8+j] = f2bf(vw[(size_t)(k0+j)*256 + c]);
    }
  } else if (idx < 24576) {                             // q: [16][8][64]
    int t = idx - 16384;
    int ct = t >> 9, dc = (t >> 6) & 7, L = t & 63;
    int col = ct*16 + (L & 15), k0 = dc*32 + ((L>>4)*8);
    for (int j = 0; j < 8; ++j) wq_[t*8+j] = f2bf(qw[(size_t)(k0+j)*256 + col]);
  } else if (idx < 73728) {                             // gru: [96][8][64]
    int t = idx - 24576;
    int ct = t >> 9, dc = (t >> 6) & 7, L = t & 63;
    int k0 = dc*32 + ((L>>4)*8);
    const float* W = (ct < 48) ? wi : wh;
    int col = ((ct < 48) ? ct : (ct - 48))*16 + (L & 15);
    for (int j = 0; j < 8; ++j) wgru[t*8+j] = f2bf(W[(size_t)(k0+j)*768 + col]);
  } else if (idx < 90112) {                             // mlp1: [32][8][64]
    int t = idx - 73728;
    int ct = t >> 9, dc = (t >> 6) & 7, L = t & 63;
    int col = ct*16 + (L & 15), k0 = dc*32 + ((L>>4)*8);
    for (int j = 0; j < 8; ++j) wm1[t*8+j] = f2bf(w1[(size_t)(k0+j)*512 + col]);
  } else if (idx < 106496) {                            // mlp2: [16][16][64]
    int t = idx - 90112;
    int ct = t >> 10, dc = (t >> 6) & 15, L = t & 63;
    int col = ct*16 + (L & 15), k0 = dc*32 + ((L>>4)*8);
    for (int j = 0; j < 8; ++j) wm2[t*8+j] = f2bf(w2[(size_t)(k0+j)*256 + col]);
  } else {                                              // slots copy (float4)
    int t = idx - 106496;
    f32x4 v = *(const f32x4*)(slot_init + (size_t)t*4);
    *(f32x4*)(slots + (size_t)t*4) = v;
  }
}

// ---------------------------------------------------------------------------
// gemm_kv R5: 4096 blocks x 512 thr. Block = 64 tokens x all 512 out cols.
// Wave w owns ct = 4w..4w+3 (64 cols) across 4 token tiles: acc[4][4] = 64
// AGPR (16 waves/CU reg cap), each B-frag load feeds 4 MFMAs.
// Phases: LN-stage | MFMA | concurrent K+V scatter | coalesced store |
//         FUSED iter-0 QK (waves 0-3, K image read back from LDS) | P store.
// K image chunk permutation: pi = o1*32 | r*8 | o0*4 | q  (conflict-free)
// ---------------------------------------------------------------------------
__global__ __launch_bounds__(512, 4) void gemm_kv(
    const float* __restrict__ x, const float* __restrict__ lng,
    const float* __restrict__ lnb, const unsigned short* __restrict__ wkv,
    const unsigned short* __restrict__ qfg,
    unsigned short* __restrict__ kfr, unsigned short* __restrict__ vfr,
    unsigned short* __restrict__ Pg)
{
  // 64 KB: A-tile 64x264 shorts (33.8 KB), then reused as
  //        K img shorts [0,16384) + V img shorts [16384,32768)
  __shared__ unsigned short smem[32768];
  __shared__ unsigned short pimg[512];    // packed P: [2 c][32 pos][8 j]
  int tid = threadIdx.x, w = tid >> 6, L = tid & 63;
  int m16 = L & 15, q = L >> 4;
  int blk = blockIdx.x;
  int b = blk >> 6;
  int n0 = (blk & 63) << 6;

  { // fused LN + stage bf16 A tile. wave w: rows w*8..w*8+7; 8 thr/row
    int r = (w << 3) + (L & 7), t8 = L >> 3;
    const float* xr = x + ((size_t)((b << 12) + n0 + r) << 8) + (t8 << 5);
    float xv[32];
    float s = 0.f, s2 = 0.f;
#pragma unroll
    for (int i = 0; i < 8; ++i) {
      f32x4 v = *(const f32x4*)(xr + (i << 2));
#pragma unroll
      for (int jj = 0; jj < 4; ++jj) { float t = v[jj]; xv[i*4+jj] = t; s += t; s2 += t*t; }
    }
    s  += __shfl_xor(s, 8);  s  += __shfl_xor(s, 16);  s  += __shfl_xor(s, 32);
    s2 += __shfl_xor(s2, 8); s2 += __shfl_xor(s2, 16); s2 += __shfl_xor(s2, 32);
    float mean = s * 0.00390625f;
    float var  = s2 * 0.00390625f - mean * mean;
    float rstd = rsqrtf(fmaxf(var, 0.f) + 1e-5f);
    unsigned short* arow = smem + r * 264 + (t8 << 5);
    const float* gg = lng + (t8 << 5);
    const float* bb = lnb + (t8 << 5);
#pragma unroll
    for (int i = 0; i < 4; ++i) {
      f32x4 g0 = *(const f32x4*)(gg + (i << 3));
      f32x4 g1 = *(const f32x4*)(gg + (i << 3) + 4);
      f32x4 b0 = *(const f32x4*)(bb + (i << 3));
      f32x4 b1 = *(const f32x4*)(bb + (i << 3) + 4);
      us8 pk;
#pragma unroll
      for (int jj = 0; jj < 4; ++jj) {
        pk[jj]     = f2bf((xv[i*8+jj]   - mean) * rstd * g0[jj] + b0[jj]);
        pk[4 + jj] = f2bf((xv[i*8+4+jj] - mean) * rstd * g1[jj] + b1[jj]);
      }
      *(us8*)(arow + (i << 3)) = pk;
    }
  }
  __syncthreads();

  f32x4 acc[4][4];
#pragma unroll
  for (int mt = 0; mt < 4; ++mt)
#pragma unroll
    for (int c = 0; c < 4; ++c) acc[mt][c] = (f32x4){0.f,0.f,0.f,0.f};

  __builtin_amdgcn_s_setprio(1);
#pragma unroll
  for (int dc = 0; dc < 8; ++dc) {
    short8 af[4];
#pragma unroll
    for (int mt = 0; mt < 4; ++mt)
      af[mt] = *(const short8*)(smem + ((mt << 4) + m16) * 264 + dc*32 + q*8);
#pragma unroll
    for (int c = 0; c < 4; ++c) {
      short8 bf = *(const short8*)(wkv + ((((w<<2)+c)*8 + dc)*64 + L) * 8);
#pragma unroll
      for (int mt = 0; mt < 4; ++mt)
        acc[mt][c] = mfma16(af[mt], bf, acc[mt][c]);
    }
  }
  __builtin_amdgcn_s_setprio(0);
  __syncthreads();   // A-tile dead; reuse smem for both images

  if (w < 4) {          // K image: cols 0..255, chunk pos = pi(oct,r,q)
#pragma unroll
    for (int mt = 0; mt < 4; ++mt)
#pragma unroll
      for (int c = 0; c < 4; ++c) {
        int col = (w << 6) + (c << 4) + m16;
        int dc = col >> 5, oct = (col >> 3) & 3, j = col & 7;
        int base = ((mt << 3) + dc)*64 + ((oct >> 1) << 5) + ((oct & 1) << 2) + q;
#pragma unroll
        for (int r = 0; r < 4; ++r)
          smem[(base + (r << 3))*8 + j] = f2bf(acc[mt][c][r]);
      }
  } else {              // V image: cols 256..511 -> d-major (transposed) A-frag
#pragma unroll
    for (int mt = 0; mt < 4; ++mt)
#pragma unroll
      for (int c = 0; c < 4; ++c) {
        int d = ((w - 4) << 6) + (c << 4) + m16;
        int dt = d >> 4;
        int tok = ((mt & 1) << 4) + (q << 2);
        int lp = m16 + ((tok >> 3) << 4), j0 = (q & 1) << 2;
        us4 pk;
#pragma unroll
        for (int r = 0; r < 4; ++r) pk[r] = f2bf(acc[mt][c][r]);
        *(us4*)&smem[16384 + ((mt >> 1) << 13) + ((dt << 6) + lp)*8 + j0] = pk;
      }
  }
  __syncthreads();
  { // store K image (coalesced, 2048 us8)
    size_t kb = (size_t)b*256 + ((blk & 63) << 2);
#pragma unroll
    for (int ii = 0; ii < 4; ++ii) {
      int cix = ii*512 + tid;
      int rt = cix >> 9, dcs = (cix >> 6) & 7, p = cix & 63;
      short8 vv = *(const short8*)(smem + (size_t)cix*8);
      *(short8*)(kfr + (((kb + rt)*8 + dcs)*64 + p)*8) = vv;
    }
    // store V image (coalesced, 2048 us8)
    size_t vb = (size_t)b*128 + ((blk & 63) << 1);
#pragma unroll
    for (int ii = 0; ii < 4; ++ii) {
      int cix = ii*512 + tid;
      int cc = cix >> 10, dt = (cix >> 6) & 15, lp = cix & 63;
      short8 vv = *(const short8*)(smem + 16384 + (size_t)cix*8);
      *(short8*)(vfr + (((vb + cc)*16 + dt)*64 + lp)*8) = vv;
    }
  }

  // ---- fused iter-0 QK + softmax (waves 0-3; K image still live in LDS).
  // Wave w handles its local token tile mt=w (tokens 16w..16w+15).
  // LDS flat index == kfr flat index at the block's tile base, so the same
  // pk lane permutation attn uses applies.
  if (w < 4) {
    int pkL = (L & 32) | ((L & 3) << 3) | ((L & 16) >> 2) | ((L >> 2) & 3);
    const unsigned short* qb = qfg + ((size_t)b << 12);
    f32x4 d0 = (f32x4){0.f,0.f,0.f,0.f};
    __builtin_amdgcn_s_setprio(1);
#pragma unroll
    for (int dc = 0; dc < 8; ++dc) {
      short8 kf = *(const short8*)(smem + (((w << 3) + dc)*64 + pkL)*8);
      short8 qf = *(const short8*)(qb + (dc*64 + L)*8);
      d0 = mfma16(kf, qf, d0);
    }
    __builtin_amdgcn_s_setprio(0);
    // softmax over 8 slots (dots O(1): skip max-subtract), +eps
    float pv[4];
#pragma unroll
    for (int r = 0; r < 4; ++r) {
      float e = __expf(d0[r]);
      float ss = e;
      ss += __shfl_xor(ss, 1); ss += __shfl_xor(ss, 2); ss += __shfl_xor(ss, 4);
      pv[r] = e / ss + 1e-6f;
    }
    if (m16 < 8) {
      // token t = 16w + 4q + r; chunk c = w>>1; in-chunk tc = 16(w&1)+4q+r
      // packed pos' = (tc>>3)*8 + slot; j = tc&7 = 4(q&1)+r (consecutive)
      us4 pkk;
#pragma unroll
      for (int r = 0; r < 4; ++r) pkk[r] = f2bf(pv[r]);
      int c = w >> 1;
      int posp = ((2*(w & 1) + (q >> 1)) << 3) + m16;
      *(us4*)&pimg[((c << 5) + posp)*8 + ((q & 1) << 2)] = pkk;
    }
  }
  __syncthreads();
  if (tid < 64) {   // store packed P (2 chunks x 32 pos x 8 j)
    us8 vv = *(const us8*)(pimg + tid*8);
    *(us8*)(Pg + ((size_t)b*128 + ((blk & 63) << 1))*256 + tid*8) = vv;
  }
}

// ---------------------------------------------------------------------------
// attn_pv (iter 0 only): PV-only streaming. grid (16,64) x 256.
// Loads packed bf16 P B-frags written by gemm_kv; no kfr read, no QK, no
// softmax. rs recomputed from bf16 P (matches pb numerics). Lower regs
// (no qf[8]) -> 4 waves/SIMD.
// ---------------------------------------------------------------------------
__global__ __launch_bounds__(256, 4) void attn_pv(
    const unsigned short* __restrict__ vfr,
    const unsigned short* __restrict__ Pg,
    float* __restrict__ accp, float* __restrict__ sump)
{
  __shared__ float red[4][8][260];
  __shared__ float rsum[4][8];
  int tid = threadIdx.x, w = tid >> 6, L = tid & 63;
  int slot = L & 15, q = L >> 4;
  int bt = blockIdx.x, b = blockIdx.y;
  int wv = (bt << 2) + w;
  const unsigned short* vbp = vfr + ((size_t)b << 20) + L*8;
  const unsigned short* Pb = Pg + ((size_t)b << 15);
  f32x4 accU[16];
#pragma unroll
  for (int dt = 0; dt < 16; ++dt) accU[dt] = (f32x4){0.f,0.f,0.f,0.f};
  float rs = 0.f;

#pragma unroll
  for (int c = 0; c < 2; ++c) {
    int c32 = (wv << 1) + c;
    const unsigned short* vt = vbp + (size_t)c32 * 8192;
    short8 pb = (short8){0,0,0,0,0,0,0,0};
    if (slot < 8) {
      pb = *(const short8*)(Pb + (((size_t)c32 << 5) + (q << 3) + slot)*8);
#pragma unroll
      for (int j = 0; j < 8; ++j) rs += bf2f((unsigned short)pb[j]);
    }
    __builtin_amdgcn_s_setprio(1);
#pragma unroll
    for (int dt = 0; dt < 16; ++dt) {
      short8 vv = *(const short8*)(vt + dt*512);
      accU[dt] = mfma16(vv, pb, accU[dt]);
    }
    __builtin_amdgcn_s_setprio(0);
  }
  rs += __shfl_xor(rs, 16);
  rs += __shfl_xor(rs, 32);
  if (slot < 8) {
#pragma unroll
    for (int dt = 0; dt < 16; ++dt)
      *(f32x4*)&red[w][slot][dt*16 + (q << 2)] = accU[dt];
  }
  if (L < 8) rsum[w][L] = rs;
  __syncthreads();
  { // block reduction over 4 waves -> one partial per block
    int s = tid >> 5, dp = (tid & 31) << 3;
    f32x4 a0 = (f32x4){0.f,0.f,0.f,0.f}, a1 = (f32x4){0.f,0.f,0.f,0.f};
#pragma unroll
    for (int ww = 0; ww < 4; ++ww) {
      a0 += *(const f32x4*)&red[ww][s][dp];
      a1 += *(const f32x4*)&red[ww][s][dp + 4];
    }
    float* ab = accp + (((size_t)((b << 4) + bt)*8 + s) << 8) + dp;
    *(f32x4*)ab = a0;
    *(f32x4*)(ab + 4) = a1;
    if (tid < 8)
      sump[(((b << 4) + bt) << 3) + tid] =
          rsum[0][tid] + rsum[1][tid] + rsum[2][tid] + rsum[3][tid];
  }
}

// ---------------------------------------------------------------------------
// attn (iters 1,2): grid (16, 64) x 256. Barrier-free main loop; wave = 64
// tokens (c<2). K chunks live at pi-permuted positions -> offset pk*8.
// Tail: cross-wave LDS reduction -> one partial per block.
// ---------------------------------------------------------------------------
__global__ __launch_bounds__(256, 3) void attn(
    const unsigned short* __restrict__ kfr,
    const unsigned short* __restrict__ vfr,
    const unsigned short* __restrict__ qfg,
    float* __restrict__ accp, float* __restrict__ sump)
{
  __shared__ float red[4][8][260];
  __shared__ float rsum[4][8];
  int tid = threadIdx.x, w = tid >> 6, L = tid & 63;
  int slot = L & 15, q = L >> 4;
  int bt = blockIdx.x, b = blockIdx.y;
  int wv = (bt << 2) + w;
  int pk = (L & 32) | ((L & 3) << 3) | ((L & 16) >> 2) | ((L >> 2) & 3);
  const unsigned short* kb = kfr + ((size_t)b << 20) + pk*8;
  const unsigned short* vbp = vfr + ((size_t)b << 20) + L*8;
  short8 qf[8];
#pragma unroll
  for (int dc = 0; dc < 8; ++dc)
    qf[dc] = *(const short8*)(qfg + ((size_t)b << 12) + (dc*64 + L)*8);
  f32x4 accU[16];
#pragma unroll
  for (int dt = 0; dt < 16; ++dt) accU[dt] = (f32x4){0.f,0.f,0.f,0.f};
  float rs = 0.f;

#pragma unroll
  for (int c = 0; c < 2; ++c) {
    int tb0 = (wv << 2) + (c << 1);
    int c32 = (wv << 1) + c;
    const unsigned short* kt = kb + (size_t)tb0 * 4096;
    const unsigned short* vt = vbp + (size_t)c32 * 8192;
    short8 vfA[8];
#pragma unroll
    for (int dt = 0; dt < 8; ++dt)
      vfA[dt] = *(const short8*)(vt + dt*512);
    f32x4 d0 = (f32x4){0.f,0.f,0.f,0.f}, d1 = (f32x4){0.f,0.f,0.f,0.f};
    __builtin_amdgcn_s_setprio(1);
#pragma unroll
    for (int dc = 0; dc < 8; ++dc) {
      short8 k0 = *(const short8*)(kt + dc*512);
      short8 k1 = *(const short8*)(kt + 4096 + dc*512);
      d0 = mfma16(k0, qf[dc], d0);
      d1 = mfma16(k1, qf[dc], d1);
    }
    __builtin_amdgcn_s_setprio(0);
    // softmax over 8 slots (dots are O(1): skip max-subtract), +eps
    float p0[4], p1[4];
#pragma unroll
    for (int r = 0; r < 4; ++r) {
      float e = __expf(d0[r]);
      float ss = e;
      ss += __shfl_xor(ss, 1); ss += __shfl_xor(ss, 2); ss += __shfl_xor(ss, 4);
      float pv = (slot < 8) ? (e / ss + 1e-6f) : 0.f;
      rs += pv; p0[r] = pv;
    }
#pragma unroll
    for (int r = 0; r < 4; ++r) {
      float e = __expf(d1[r]);
      float ss = e;
      ss += __shfl_xor(ss, 1); ss += __shfl_xor(ss, 2); ss += __shfl_xor(ss, 4);
      float pv = (slot < 8) ? (e / ss + 1e-6f) : 0.f;
      rs += pv; p1[r] = pv;
    }
    // in-wave transform to B-frag: pb[j] = P[token 8q+j][slot m16]
    short8 pb;
#pragma unroll
    for (int j = 0; j < 8; ++j) {
      int srcl = slot + ((q & 1) << 5) + ((j >> 2) << 4);
      float va = __shfl(p0[j & 3], srcl);
      float vb2 = __shfl(p1[j & 3], srcl);
      pb[j] = (short)f2bf((q >> 1) ? vb2 : va);
    }
    __builtin_amdgcn_s_setprio(1);
#pragma unroll
    for (int dt = 0; dt < 8; ++dt) accU[dt] = mfma16(vfA[dt], pb, accU[dt]);
#pragma unroll
    for (int dt = 0; dt < 8; ++dt) {
      short8 vv = *(const short8*)(vt + (8 + dt)*512);
      accU[8 + dt] = mfma16(vv, pb, accU[8 + dt]);
    }
    __builtin_amdgcn_s_setprio(0);
  }
  rs += __shfl_xor(rs, 16);
  rs += __shfl_xor(rs, 32);
  if (slot < 8) {
#pragma unroll
    for (int dt = 0; dt < 16; ++dt)
      *(f32x4*)&red[w][slot][dt*16 + (q << 2)] = accU[dt];
  }
  if (L < 8) rsum[w][L] = rs;
  __syncthreads();
  { // block reduction over 4 waves -> one partial per block
    int s = tid >> 5, dp = (tid & 31) << 3;
    f32x4 a0 = (f32x4){0.f,0.f,0.f,0.f}, a1 = (f32x4){0.f,0.f,0.f,0.f};
#pragma unroll
    for (int ww = 0; ww < 4; ++ww) {
      a0 += *(const f32x4*)&red[ww][s][dp];
      a1 += *(const f32x4*)&red[ww][s][dp + 4];
    }
    float* ab = accp + (((size_t)((b << 4) + bt)*8 + s) << 8) + dp;
    *(f32x4*)ab = a0;
    *(f32x4*)(ab + 4) = a1;
    if (tid < 8)
      sump[(((b << 4) + bt) << 3) + tid] =
          rsum[0][tid] + rsum[1][tid] + rsum[2][tid] + rsum[3][tid];
  }
}

// ---------------------------------------------------------------------------
// fuse: 64 blocks (one per batch). mode1: reduce 16 partials -> updates ->
// GRU -> LN -> MLP -> residual -> slots (+out). Always: pack next-iter q.
// ---------------------------------------------------------------------------
DEV void ln_stats16(const float hpr[16][260], float stats[16][2], int tid) {
  int row = tid >> 4, seg = tid & 15;
  float s = 0.f, s2 = 0.f;
#pragma unroll
  for (int jj = 0; jj < 16; ++jj) { float v = hpr[row][seg*16 + jj]; s += v; s2 += v*v; }
  s  += __shfl_xor(s, 1);  s  += __shfl_xor(s, 2);  s  += __shfl_xor(s, 4);  s  += __shfl_xor(s, 8);
  s2 += __shfl_xor(s2, 1); s2 += __shfl_xor(s2, 2); s2 += __shfl_xor(s2, 4); s2 += __shfl_xor(s2, 8);
  if (seg == 0) {
    float mean = s * 0.00390625f;
    float var  = s2 * 0.00390625f - mean*mean;
    stats[row][0] = mean;
    stats[row][1] = rsqrtf(fmaxf(var, 0.f) + 1e-5f);
  }
}

__global__ __launch_bounds__(256, 2) void fuse(
    int mode, int last,
    float* __restrict__ slots,
    const float* __restrict__ accp, const float* __restrict__ sump,
    const unsigned short* __restrict__ wgru,
    const unsigned short* __restrict__ wm1,
    const unsigned short* __restrict__ wm2,
    const unsigned short* __restrict__ wq_,
    unsigned short* __restrict__ qfg,
    const float* __restrict__ gbi, const float* __restrict__ gbh,
    const float* __restrict__ lnsg, const float* __restrict__ lnsb,
    const float* __restrict__ lnfg, const float* __restrict__ lnfb,
    const float* __restrict__ mb1, const float* __restrict__ mb2,
    float* __restrict__ outp)
{
  __shared__ unsigned short uimg[4096];   // [8 dc][64][8] A-frag image (reused 3x)
  __shared__ unsigned short himg[4096];
  __shared__ unsigned short h1img[8192];  // [16 dc][64][8]
  __shared__ float hpr[16][260];
  __shared__ float stats[16][2];
  __shared__ float rowsum[8];
  int tid = threadIdx.x, w = tid >> 6, L = tid & 63;
  int m16 = L & 15, q = L >> 4;
  int b = blockIdx.x;
  for (int i = tid; i < 4096; i += 256) { uimg[i] = 0; himg[i] = 0; }
  __syncthreads();
  float hh[4][4];

  if (mode == 1) {
    if (tid < 8) {
      float s = 0.f;
      for (int p = 0; p < 16; ++p) s += sump[((b << 4) + p)*8 + tid];
      rowsum[tid] = s;
    }
    __syncthreads();
    { // reduce 16 block-partials -> updates, pack A-frag images (updates + prev)
      int s = tid >> 5, dp = (tid & 31) << 3;
      const float* base = accp + (((size_t)(b << 4)*8 + s) << 8) + dp;
      f32x4 a0 = (f32x4){0.f,0.f,0.f,0.f}, a1 = (f32x4){0.f,0.f,0.f,0.f};
      for (int p = 0; p < 16; ++p) {
        const float* pp = base + (size_t)p * 2048;
        a0 += *(const f32x4*)pp;
        a1 += *(const f32x4*)(pp + 4);
      }
      float inv = 1.f / rowsum[s];
      us8 pk;
#pragma unroll
      for (int j = 0; j < 4; ++j) { pk[j] = f2bf(a0[j]*inv); pk[4+j] = f2bf(a1[j]*inv); }
      int dc = dp >> 5, lp = s + ((dp >> 3) & 3)*16;
      *(us8*)&uimg[(dc*64 + lp)*8] = pk;
      const float* sl = slots + ((b << 3) + s)*256 + dp;
      f32x4 h0 = *(const f32x4*)sl;
      f32x4 h1 = *(const f32x4*)(sl + 4);
      us8 pk2;
#pragma unroll
      for (int j = 0; j < 4; ++j) { pk2[j] = f2bf(h0[j]); pk2[4+j] = f2bf(h1[j]); }
      *(us8*)&himg[(dc*64 + lp)*8] = pk2;
    }
    __syncthreads();
    // GRU MFMA: wave w owns d-tiles 4w..4w+3; gates r/z/n col-local per d
    f32x4 aI[4][3], aH[4][3];
#pragma unroll
    for (int i = 0; i < 4; ++i)
#pragma unroll
      for (int g = 0; g < 3; ++g) { aI[i][g] = (f32x4){0.f,0.f,0.f,0.f}; aH[i][g] = (f32x4){0.f,0.f,0.f,0.f}; }
#pragma unroll
    for (int dc = 0; dc < 8; ++dc) {
      short8 au = *(const short8*)(uimg + (dc*64 + L)*8);
      short8 ah = *(const short8*)(himg + (dc*64 + L)*8);
#pragma unroll
      for (int i = 0; i < 4; ++i) {
        int dt = (w << 2) + i;
#pragma unroll
        for (int g = 0; g < 3; ++g) {
          short8 bu = *(const short8*)(wgru + (((g*16 + dt)*8 + dc)*64 + L)*8);
          aI[i][g] = mfma16(au, bu, aI[i][g]);
          short8 bh = *(const short8*)(wgru + (((48 + g*16 + dt)*8 + dc)*64 + L)*8);
          aH[i][g] = mfma16(ah, bh, aH[i][g]);
        }
      }
    }
#pragma unroll
    for (int i = 0; i < 4; ++i) {
      int d = ((w << 2) + i)*16 + m16;
      float bir = gbi[d], biz = gbi[256+d], bin = gbi[512+d];
      float bhr = gbh[d], bhz = gbh[256+d], bhn = gbh[512+d];
#pragma unroll
      for (int r = 0; r < 4; ++r) {
        int s = (q << 2) + r;
        if (s < 8) {
          float ir = aI[i][0][r] + bir, iz = aI[i][1][r] + biz, in_ = aI[i][2][r] + bin;
          float hr = aH[i][0][r] + bhr, hz = aH[i][1][r] + bhz, hn = aH[i][2][r] + bhn;
          float rg = 1.f / (1.f + __expf(-(ir + hr)));
          float zg = 1.f / (1.f + __expf(-(iz + hz)));
          float nn = tanhf(in_ + rg * hn);
          float hv = slots[((b << 3) + s)*256 + d];
          float hp = (1.f - zg)*nn + zg*hv;
          hh[i][r] = hp;
          hpr[s][d] = hp;
        } else {
          hpr[s][d] = 0.f;
        }
      }
    }
    __syncthreads();
    ln_stats16(hpr, stats, tid);
    __syncthreads();
    { // LN_ff -> A image
      int s = tid >> 5, dp = (tid & 31) << 3;
      float mean = stats[s][0], rstd = stats[s][1];
      us8 pk;
#pragma unroll
      for (int j = 0; j < 8; ++j)
        pk[j] = f2bf((hpr[s][dp+j] - mean)*rstd*lnfg[dp+j] + lnfb[dp+j]);
      int dc = dp >> 5, lp = s + ((dp >> 3) & 3)*16;
      *(us8*)&uimg[(dc*64 + lp)*8] = pk;
    }
    __syncthreads();
    // MLP layer 1 (relu) -> h1 A-frag image (K=512)
    f32x4 a1[8];
#pragma unroll
    for (int c = 0; c < 8; ++c) a1[c] = (f32x4){0.f,0.f,0.f,0.f};
#pragma unroll
    for (int dc = 0; dc < 8; ++dc) {
      short8 aa = *(const short8*)(uimg + (dc*64 + L)*8);
#pragma unroll
      for (int c = 0; c < 8; ++c) {
        short8 bb = *(const short8*)(wm1 + ((((w<<3)+c)*8 + dc)*64 + L)*8);
        a1[c] = mfma16(aa, bb, a1[c]);
      }
    }
#pragma unroll
    for (int c = 0; c < 8; ++c) {
      int col = ((w << 3) + c)*16 + m16;
      float bv = mb1[col];
      int dc2 = col >> 5, lpb = ((col >> 3) & 3)*16, j = col & 7;
#pragma unroll
      for (int r = 0; r < 4; ++r) {
        int s = (q << 2) + r;
        float v = (s < 8) ? fmaxf(a1[c][r] + bv, 0.f) : 0.f;
        h1img[(dc2*64 + s + lpb)*8 + j] = f2bf(v);
      }
    }
    __syncthreads();
    // MLP layer 2 + residual; wave's col tiles == its GRU d-tiles
    f32x4 a2[4];
#pragma unroll
    for (int i = 0; i < 4; ++i) a2[i] = (f32x4){0.f,0.f,0.f,0.f};
#pragma unroll
    for (int dc2 = 0; dc2 < 16; ++dc2) {
      short8 aa = *(const short8*)(h1img + (dc2*64 + L)*8);
#pragma unroll
      for (int i = 0; i < 4; ++i) {
        short8 bb = *(const short8*)(wm2 + ((((w<<2)+i)*16 + dc2)*64 + L)*8);
        a2[i] = mfma16(aa, bb, a2[i]);
      }
    }
#pragma unroll
    for (int i = 0; i < 4; ++i) {
      int d = ((w << 2) + i)*16 + m16;
      float b2v = mb2[d];
#pragma unroll
      for (int r = 0; r < 4; ++r) {
        int s = (q << 2) + r;
        if (s < 8) {
          float o = a2[i][r] + b2v + hh[i][r];
          slots[((b << 3) + s)*256 + d] = o;
          if (last) outp[((b << 3) + s)*256 + d] = o;
          hpr[s][d] = o;
        }
      }
    }
    __syncthreads();
  } else {
    int s = tid >> 5, dp = (tid & 31) << 3;
#pragma unroll
    for (int j = 0; j < 8; ++j) {
      hpr[s][dp+j] = slots[((b << 3) + s)*256 + dp + j];
      hpr[8 + s][dp+j] = 0.f;
    }
    __syncthreads();
  }

  // q for next attention pass: LN_slots -> @q_w -> B-frag-direct global image
  ln_stats16(hpr, stats, tid);
  __syncthreads();
  {
    int s = tid >> 5, dp = (tid & 31) << 3;
    float mean = stats[s][0], rstd = stats[s][1];
    us8 pk;
#pragma unroll
    for (int j = 0; j < 8; ++j)
      pk[j] = f2bf((hpr[s][dp+j] - mean)*rstd*lnsg[dp+j] + lnsb[dp+j]);
    int dc = dp >> 5, lp = s + ((dp >> 3) & 3)*16;
    *(us8*)&uimg[(dc*64 + lp)*8] = pk;
  }
  __syncthreads();
  {
    f32x4 aq[4];
#pragma unroll
    for (int i = 0; i < 4; ++i) aq[i] = (f32x4){0.f,0.f,0.f,0.f};
#pragma unroll
    for (int dc = 0; dc < 8; ++dc) {
      short8 aa = *(const short8*)(uimg + (dc*64 + L)*8);
#pragma unroll
      for (int i = 0; i < 4; ++i) {
        short8 bb = *(const short8*)(wq_ + ((((w<<2)+i)*8 + dc)*64 + L)*8);
        aq[i] = mfma16(aa, bb, aq[i]);
      }
    }
    unsigned short* qb = qfg + ((size_t)b << 12);
#pragma unroll
    for (int i = 0; i < 4; ++i) {
      int col = ((w << 2) + i)*16 + m16;
      int dc = col >> 5, lpb = ((col >> 3) & 3)*16, j = col & 7;
#pragma unroll
      for (int r = 0; r < 4; ++r) {
        int s = (q << 2) + r;
        qb[(dc*64 + s + lpb)*8 + j] = (s < 8) ? f2bf(aq[i][r]) : (unsigned short)0;
      }
    }
  }
}

// ---------------------------------------------------------------------------
extern "C" void kernel_launch(void* const* d_in, const int* in_sizes, int n_in,
                              void* d_out, int out_size, void* d_ws, size_t ws_size,
                              hipStream_t stream) {
  (void)in_sizes; (void)n_in; (void)out_size;
  if (ws_size < WS_NEED) return;   // workspace guard (need ~275 MB)

  const float* inputs    = (const float*)d_in[0];
  const float* slot_init = (const float*)d_in[1];
  const float* k_w       = (const float*)d_in[2];
  const float* q_w       = (const float*)d_in[3];
  const float* v_w       = (const float*)d_in[4];
  const float* gru_wi    = (const float*)d_in[5];
  const float* gru_wh    = (const float*)d_in[6];
  const float* gru_bi    = (const float*)d_in[7];
  const float* gru_bh    = (const float*)d_in[8];
  const float* ln_in_g   = (const float*)d_in[9];
  const float* ln_in_b   = (const float*)d_in[10];
  const float* ln_s_g    = (const float*)d_in[11];
  const float* ln_s_b    = (const float*)d_in[12];
  const float* ln_f_g    = (const float*)d_in[13];
  const float* ln_f_b    = (const float*)d_in[14];
  const float* m_w1      = (const float*)d_in[15];
  const float* m_b1      = (const float*)d_in[16];
  const float* m_w2      = (const float*)d_in[17];
  const float* m_b2      = (const float*)d_in[18];

  char* ws = (char*)d_ws;
  unsigned short* kfr  = (unsigned short*)(ws + O_KF);
  unsigned short* vfr  = (unsigned short*)(ws + O_VF);
  float*          accp = (float*)(ws + O_ACC);
  unsigned short* Pg   = (unsigned short*)(ws + O_P);
  float*          sump = (float*)(ws + O_SUM);
  float*          slots= (float*)(ws + O_SL);
  unsigned short* qfg  = (unsigned short*)(ws + O_QF);
  unsigned short* wkv  = (unsigned short*)(ws + O_WKV);
  unsigned short* wq_  = (unsigned short*)(ws + O_WQ);
  unsigned short* wgru = (unsigned short*)(ws + O_WGRU);
  unsigned short* wm1  = (unsigned short*)(ws + O_WM1);
  unsigned short* wm2  = (unsigned short*)(ws + O_WM2);

  prepack<<<544, 256, 0, stream>>>(k_w, q_w, v_w, gru_wi, gru_wh, m_w1, m_w2,
                                   slot_init, wkv, wq_, wgru, wm1, wm2, slots);
  // q for iteration 0 (needs only slots) BEFORE gemm_kv, which now consumes it
  fuse<<<64, 256, 0, stream>>>(0, 0, slots, accp, sump, wgru, wm1, wm2, wq_, qfg,
                               gru_bi, gru_bh, ln_s_g, ln_s_b, ln_f_g, ln_f_b,
                               m_b1, m_b2, (float*)d_out);
  gemm_kv<<<4096, 512, 0, stream>>>(inputs, ln_in_g, ln_in_b, wkv, qfg,
                                    kfr, vfr, Pg);
  // iteration 0: PV-only (QK+softmax already done inside gemm_kv)
  attn_pv<<<dim3(16, 64), 256, 0, stream>>>(vfr, Pg, accp, sump);
  fuse<<<64, 256, 0, stream>>>(1, 0, slots, accp, sump, wgru, wm1, wm2, wq_,
                               qfg, gru_bi, gru_bh, ln_s_g, ln_s_b, ln_f_g,
                               ln_f_b, m_b1, m_b2, (float*)d_out);
  for (int it = 1; it < 3; ++it) {
    attn<<<dim3(16, 64), 256, 0, stream>>>(kfr, vfr, qfg, accp, sump);
    fuse<<<64, 256, 0, stream>>>(1, (it == 2) ? 1 : 0, slots, accp, sump, wgru,
                                 wm1, wm2, wq_, qfg, gru_bi, gru_bh, ln_s_g,
                                 ln_s_b, ln_f_g, ln_f_b, m_b1, m_b2,
                                 (float*)d_out);
  }
}

// Round 3
// 718.941 us; speedup vs baseline: 1.2793x; 1.2793x over previous
//
#include <hip/hip_runtime.h>
#include <cstdint>
#include <cstddef>

// ---------------------------------------------------------------------------
// SlotAttention on MI355X.
//  (1) prepack: bf16 weight images in MFMA B-fragment order; slot_init copy.
//  (2) gemm_kv: x=LN(inputs); [k|v] = x @ [k_w/16 | v_w] via bf16 MFMA.
//      64-token blocks, 512 thr (8 waves), acc[4][4], concurrent K+V scatter.
//      (R5's fused-QK tail reverted: it cost +21us and saved nothing — R2
//      measured attn_pv == attn, so attention is not QK/K-stream bound.)
//  (3) attn: barrier-free main loop; 64 tok/wave, cross-wave LDS reduction.
//  (4) fuse R6: 512 threads (8 waves, 2 waves/SIMD). All MFMA phases split
//      across 2x waves (GRU 96 MFMA/lane, MLP1 32, MLP2 32, q 16); pack/LN
//      phases at 4 floats/thread. Attacks fuse's 1-wave/SIMD latency floor.
// ---------------------------------------------------------------------------

typedef __attribute__((ext_vector_type(8))) short short8;
typedef __attribute__((ext_vector_type(4))) float f32x4;
typedef __attribute__((ext_vector_type(4))) unsigned short us4;
typedef __attribute__((ext_vector_type(8))) unsigned short us8;

#define DEV static __device__ __forceinline__

DEV unsigned short f2bf(float f) {
  union { float f; unsigned int u; } v; v.f = f;
  unsigned int r = v.u + 0x7FFFu + ((v.u >> 16) & 1u);
  return (unsigned short)(r >> 16);
}

DEV f32x4 mfma16(short8 a, short8 b, f32x4 c) {
  return __builtin_amdgcn_mfma_f32_16x16x32_bf16(a, b, c, 0, 0, 0);
}

// ---------------- workspace layout (bytes) ----------------
constexpr size_t O_KF   = 0;                                  // k frags: [64][256 tb][8 dc][64 chunk(pi)][8] bf16
constexpr size_t SZ_KF  = (size_t)64*256*8*64*8*2;            // 128 MB
constexpr size_t O_VF   = O_KF + SZ_KF;                       // v frags: [64][128 c32][16 dt][64][8] bf16
constexpr size_t SZ_VF  = (size_t)64*128*16*64*8*2;           // 128 MB
constexpr size_t O_ACC  = O_VF + SZ_VF;                       // [64][16 blk][8][256] f32 (8.4 MB used)
constexpr size_t SZ_ACC = (size_t)64*32*8*256*4;              // 16 MB reserved
constexpr size_t O_SUM  = O_ACC + SZ_ACC;                     // [64][16][8] f32
constexpr size_t SZ_SUM = (size_t)64*32*8*4;
constexpr size_t O_SL   = O_SUM + SZ_SUM;                     // slots [64][8][256] f32
constexpr size_t SZ_SL  = (size_t)64*8*256*4;
constexpr size_t O_QF   = O_SL + SZ_SL;                       // q frags [64][8 dc][64][8] bf16
constexpr size_t SZ_QF  = (size_t)64*8*64*8*2;
constexpr size_t O_WKV  = O_QF + SZ_QF;                       // [32 ct][8 dc][64][8]
constexpr size_t SZ_WKV = (size_t)32*8*64*8*2;
constexpr size_t O_WQ   = O_WKV + SZ_WKV;                     // [16][8][64][8]
constexpr size_t SZ_WQ  = (size_t)16*8*64*8*2;
constexpr size_t O_WGRU = O_WQ + SZ_WQ;                       // [96][8][64][8] (wi:0-47, wh:48-95)
constexpr size_t SZ_WGRU= (size_t)96*8*64*8*2;
constexpr size_t O_WM1  = O_WGRU + SZ_WGRU;                   // [32][8][64][8]
constexpr size_t SZ_WM1 = (size_t)32*8*64*8*2;
constexpr size_t O_WM2  = O_WM1 + SZ_WM1;                     // [16][16][64][8]
constexpr size_t SZ_WM2 = (size_t)16*16*64*8*2;
constexpr size_t WS_NEED= O_WM2 + SZ_WM2;                     // ~275 MB

// ---------------------------------------------------------------------------
// prepack: weight fragment images + slots init. 544 blocks x 256.
// B-frag convention: lane L holds W[k = dc*32 + (L>>4)*8 + j][col = ct*16 + (L&15)]
// ---------------------------------------------------------------------------
__global__ void prepack(
    const float* __restrict__ kw, const float* __restrict__ qw,
    const float* __restrict__ vw, const float* __restrict__ wi,
    const float* __restrict__ wh, const float* __restrict__ w1,
    const float* __restrict__ w2, const float* __restrict__ slot_init,
    unsigned short* __restrict__ wkv, unsigned short* __restrict__ wq_,
    unsigned short* __restrict__ wgru, unsigned short* __restrict__ wm1,
    unsigned short* __restrict__ wm2, float* __restrict__ slots)
{
  int idx = blockIdx.x * 256 + threadIdx.x;
  if (idx < 16384) {                                    // kv: [32][8][64]
    int ct = idx >> 9, dc = (idx >> 6) & 7, L = idx & 63;
    int col = ct*16 + (L & 15), k0 = dc*32 + ((L>>4)*8);
    if (col < 256) {
      for (int j = 0; j < 8; ++j) wkv[idx*8+j] = f2bf(kw[(size_t)(k0+j)*256 + col] * 0.0625f);
    } else {
      int c = col - 256;
      for (int j = 0; j < 8; ++j) wkv[idx*8+j] = f2bf(vw[(size_t)(k0+j)*256 + c]);
    }
  } else if (idx < 24576) {                             // q: [16][8][64]
    int t = idx - 16384;
    int ct = t >> 9, dc = (t >> 6) & 7, L = t & 63;
    int col = ct*16 + (L & 15), k0 = dc*32 + ((L>>4)*8);
    for (int j = 0; j < 8; ++j) wq_[t*8+j] = f2bf(qw[(size_t)(k0+j)*256 + col]);
  } else if (idx < 73728) {                             // gru: [96][8][64]
    int t = idx - 24576;
    int ct = t >> 9, dc = (t >> 6) & 7, L = t & 63;
    int k0 = dc*32 + ((L>>4)*8);
    const float* W = (ct < 48) ? wi : wh;
    int col = ((ct < 48) ? ct : (ct - 48))*16 + (L & 15);
    for (int j = 0; j < 8; ++j) wgru[t*8+j] = f2bf(W[(size_t)(k0+j)*768 + col]);
  } else if (idx < 90112) {                             // mlp1: [32][8][64]
    int t = idx - 73728;
    int ct = t >> 9, dc = (t >> 6) & 7, L = t & 63;
    int col = ct*16 + (L & 15), k0 = dc*32 + ((L>>4)*8);
    for (int j = 0; j < 8; ++j) wm1[t*8+j] = f2bf(w1[(size_t)(k0+j)*512 + col]);
  } else if (idx < 106496) {                            // mlp2: [16][16][64]
    int t = idx - 90112;
    int ct = t >> 10, dc = (t >> 6) & 15, L = t & 63;
    int col = ct*16 + (L & 15), k0 = dc*32 + ((L>>4)*8);
    for (int j = 0; j < 8; ++j) wm2[t*8+j] = f2bf(w2[(size_t)(k0+j)*256 + col]);
  } else {                                              // slots copy (float4)
    int t = idx - 106496;
    f32x4 v = *(const f32x4*)(slot_init + (size_t)t*4);
    *(f32x4*)(slots + (size_t)t*4) = v;
  }
}

// ---------------------------------------------------------------------------
// gemm_kv: 4096 blocks x 512 thr. Block = 64 tokens x all 512 out cols.
// Wave w owns ct = 4w..4w+3 (64 cols) across 4 token tiles: acc[4][4] = 64
// AGPR (16 waves/CU reg cap), each B-frag load feeds 4 MFMAs.
// Phases: LN-stage | MFMA | concurrent K+V scatter | coalesced store.
// K image chunk permutation: pi = o1*32 | r*8 | o0*4 | q  (conflict-free)
// ---------------------------------------------------------------------------
__global__ __launch_bounds__(512, 4) void gemm_kv(
    const float* __restrict__ x, const float* __restrict__ lng,
    const float* __restrict__ lnb, const unsigned short* __restrict__ wkv,
    unsigned short* __restrict__ kfr, unsigned short* __restrict__ vfr)
{
  // 64 KB: A-tile 64x264 shorts (33.8 KB), then reused as
  //        K img shorts [0,16384) + V img shorts [16384,32768)
  __shared__ unsigned short smem[32768];
  int tid = threadIdx.x, w = tid >> 6, L = tid & 63;
  int m16 = L & 15, q = L >> 4;
  int blk = blockIdx.x;
  int b = blk >> 6;
  int n0 = (blk & 63) << 6;

  { // fused LN + stage bf16 A tile. wave w: rows w*8..w*8+7; 8 thr/row
    int r = (w << 3) + (L & 7), t8 = L >> 3;
    const float* xr = x + ((size_t)((b << 12) + n0 + r) << 8) + (t8 << 5);
    float xv[32];
    float s = 0.f, s2 = 0.f;
#pragma unroll
    for (int i = 0; i < 8; ++i) {
      f32x4 v = *(const f32x4*)(xr + (i << 2));
#pragma unroll
      for (int jj = 0; jj < 4; ++jj) { float t = v[jj]; xv[i*4+jj] = t; s += t; s2 += t*t; }
    }
    s  += __shfl_xor(s, 8);  s  += __shfl_xor(s, 16);  s  += __shfl_xor(s, 32);
    s2 += __shfl_xor(s2, 8); s2 += __shfl_xor(s2, 16); s2 += __shfl_xor(s2, 32);
    float mean = s * 0.00390625f;
    float var  = s2 * 0.00390625f - mean * mean;
    float rstd = rsqrtf(fmaxf(var, 0.f) + 1e-5f);
    unsigned short* arow = smem + r * 264 + (t8 << 5);
    const float* gg = lng + (t8 << 5);
    const float* bb = lnb + (t8 << 5);
#pragma unroll
    for (int i = 0; i < 4; ++i) {
      f32x4 g0 = *(const f32x4*)(gg + (i << 3));
      f32x4 g1 = *(const f32x4*)(gg + (i << 3) + 4);
      f32x4 b0 = *(const f32x4*)(bb + (i << 3));
      f32x4 b1 = *(const f32x4*)(bb + (i << 3) + 4);
      us8 pk;
#pragma unroll
      for (int jj = 0; jj < 4; ++jj) {
        pk[jj]     = f2bf((xv[i*8+jj]   - mean) * rstd * g0[jj] + b0[jj]);
        pk[4 + jj] = f2bf((xv[i*8+4+jj] - mean) * rstd * g1[jj] + b1[jj]);
      }
      *(us8*)(arow + (i << 3)) = pk;
    }
  }
  __syncthreads();

  f32x4 acc[4][4];
#pragma unroll
  for (int mt = 0; mt < 4; ++mt)
#pragma unroll
    for (int c = 0; c < 4; ++c) acc[mt][c] = (f32x4){0.f,0.f,0.f,0.f};

#pragma unroll
  for (int dc = 0; dc < 8; ++dc) {
    short8 af[4];
#pragma unroll
    for (int mt = 0; mt < 4; ++mt)
      af[mt] = *(const short8*)(smem + ((mt << 4) + m16) * 264 + dc*32 + q*8);
#pragma unroll
    for (int c = 0; c < 4; ++c) {
      short8 bf = *(const short8*)(wkv + ((((w<<2)+c)*8 + dc)*64 + L) * 8);
#pragma unroll
      for (int mt = 0; mt < 4; ++mt)
        acc[mt][c] = mfma16(af[mt], bf, acc[mt][c]);
    }
  }
  __syncthreads();   // A-tile dead; reuse smem for both images

  if (w < 4) {          // K image: cols 0..255, chunk pos = pi(oct,r,q)
#pragma unroll
    for (int mt = 0; mt < 4; ++mt)
#pragma unroll
      for (int c = 0; c < 4; ++c) {
        int col = (w << 6) + (c << 4) + m16;
        int dc = col >> 5, oct = (col >> 3) & 3, j = col & 7;
        int base = ((mt << 3) + dc)*64 + ((oct >> 1) << 5) + ((oct & 1) << 2) + q;
#pragma unroll
        for (int r = 0; r < 4; ++r)
          smem[(base + (r << 3))*8 + j] = f2bf(acc[mt][c][r]);
      }
  } else {              // V image: cols 256..511 -> d-major (transposed) A-frag
#pragma unroll
    for (int mt = 0; mt < 4; ++mt)
#pragma unroll
      for (int c = 0; c < 4; ++c) {
        int d = ((w - 4) << 6) + (c << 4) + m16;
        int dt = d >> 4;
        int tok = ((mt & 1) << 4) + (q << 2);
        int lp = m16 + ((tok >> 3) << 4), j0 = (q & 1) << 2;
        us4 pk;
#pragma unroll
        for (int r = 0; r < 4; ++r) pk[r] = f2bf(acc[mt][c][r]);
        *(us4*)&smem[16384 + ((mt >> 1) << 13) + ((dt << 6) + lp)*8 + j0] = pk;
      }
  }
  __syncthreads();
  { // store K image (coalesced, 2048 us8)
    size_t kb = (size_t)b*256 + ((blk & 63) << 2);
#pragma unroll
    for (int ii = 0; ii < 4; ++ii) {
      int cix = ii*512 + tid;
      int rt = cix >> 9, dcs = (cix >> 6) & 7, p = cix & 63;
      short8 vv = *(const short8*)(smem + (size_t)cix*8);
      *(short8*)(kfr + (((kb + rt)*8 + dcs)*64 + p)*8) = vv;
    }
    // store V image (coalesced, 2048 us8)
    size_t vb = (size_t)b*128 + ((blk & 63) << 1);
#pragma unroll
    for (int ii = 0; ii < 4; ++ii) {
      int cix = ii*512 + tid;
      int cc = cix >> 10, dt = (cix >> 6) & 15, lp = cix & 63;
      short8 vv = *(const short8*)(smem + 16384 + (size_t)cix*8);
      *(short8*)(vfr + (((vb + cc)*16 + dt)*64 + lp)*8) = vv;
    }
  }
}

// ---------------------------------------------------------------------------
// attn: grid (16, 64) x 256. Barrier-free main loop; wave = 64 tokens (c<2).
// K chunks live at pi-permuted positions -> base-pointer offset pk*8.
// Tail: cross-wave LDS reduction -> one partial per block.
// ---------------------------------------------------------------------------
__global__ __launch_bounds__(256, 3) void attn(
    const unsigned short* __restrict__ kfr,
    const unsigned short* __restrict__ vfr,
    const unsigned short* __restrict__ qfg,
    float* __restrict__ accp, float* __restrict__ sump)
{
  __shared__ float red[4][8][260];
  __shared__ float rsum[4][8];
  int tid = threadIdx.x, w = tid >> 6, L = tid & 63;
  int slot = L & 15, q = L >> 4;
  int bt = blockIdx.x, b = blockIdx.y;
  int wv = (bt << 2) + w;
  int pk = (L & 32) | ((L & 3) << 3) | ((L & 16) >> 2) | ((L >> 2) & 3);
  const unsigned short* kb = kfr + ((size_t)b << 20) + pk*8;
  const unsigned short* vbp = vfr + ((size_t)b << 20) + L*8;
  short8 qf[8];
#pragma unroll
  for (int dc = 0; dc < 8; ++dc)
    qf[dc] = *(const short8*)(qfg + ((size_t)b << 12) + (dc*64 + L)*8);
  f32x4 accU[16];
#pragma unroll
  for (int dt = 0; dt < 16; ++dt) accU[dt] = (f32x4){0.f,0.f,0.f,0.f};
  float rs = 0.f;

#pragma unroll
  for (int c = 0; c < 2; ++c) {
    int tb0 = (wv << 2) + (c << 1);
    int c32 = (wv << 1) + c;
    const unsigned short* kt = kb + (size_t)tb0 * 4096;
    const unsigned short* vt = vbp + (size_t)c32 * 8192;
    short8 vfA[8];
#pragma unroll
    for (int dt = 0; dt < 8; ++dt)
      vfA[dt] = *(const short8*)(vt + dt*512);
    f32x4 d0 = (f32x4){0.f,0.f,0.f,0.f}, d1 = (f32x4){0.f,0.f,0.f,0.f};
#pragma unroll
    for (int dc = 0; dc < 8; ++dc) {
      short8 k0 = *(const short8*)(kt + dc*512);
      short8 k1 = *(const short8*)(kt + 4096 + dc*512);
      d0 = mfma16(k0, qf[dc], d0);
      d1 = mfma16(k1, qf[dc], d1);
    }
    // softmax over 8 slots (dots are O(1): skip max-subtract), +eps
    float p0[4], p1[4];
#pragma unroll
    for (int r = 0; r < 4; ++r) {
      float e = __expf(d0[r]);
      float ss = e;
      ss += __shfl_xor(ss, 1); ss += __shfl_xor(ss, 2); ss += __shfl_xor(ss, 4);
      float pv = (slot < 8) ? (e / ss + 1e-6f) : 0.f;
      rs += pv; p0[r] = pv;
    }
#pragma unroll
    for (int r = 0; r < 4; ++r) {
      float e = __expf(d1[r]);
      float ss = e;
      ss += __shfl_xor(ss, 1); ss += __shfl_xor(ss, 2); ss += __shfl_xor(ss, 4);
      float pv = (slot < 8) ? (e / ss + 1e-6f) : 0.f;
      rs += pv; p1[r] = pv;
    }
    // in-wave transform to B-frag: pb[j] = P[token 8q+j][slot m16]
    short8 pb;
#pragma unroll
    for (int j = 0; j < 8; ++j) {
      int srcl = slot + ((q & 1) << 5) + ((j >> 2) << 4);
      float va = __shfl(p0[j & 3], srcl);
      float vb2 = __shfl(p1[j & 3], srcl);
      pb[j] = (short)f2bf((q >> 1) ? vb2 : va);
    }
#pragma unroll
    for (int dt = 0; dt < 8; ++dt) accU[dt] = mfma16(vfA[dt], pb, accU[dt]);
#pragma unroll
    for (int dt = 0; dt < 8; ++dt) {
      short8 vv = *(const short8*)(vt + (8 + dt)*512);
      accU[8 + dt] = mfma16(vv, pb, accU[8 + dt]);
    }
  }
  rs += __shfl_xor(rs, 16);
  rs += __shfl_xor(rs, 32);
  if (slot < 8) {
#pragma unroll
    for (int dt = 0; dt < 16; ++dt)
      *(f32x4*)&red[w][slot][dt*16 + (q << 2)] = accU[dt];
  }
  if (L < 8) rsum[w][L] = rs;
  __syncthreads();
  { // block reduction over 4 waves -> one partial per block
    int s = tid >> 5, dp = (tid & 31) << 3;
    f32x4 a0 = (f32x4){0.f,0.f,0.f,0.f}, a1 = (f32x4){0.f,0.f,0.f,0.f};
#pragma unroll
    for (int ww = 0; ww < 4; ++ww) {
      a0 += *(const f32x4*)&red[ww][s][dp];
      a1 += *(const f32x4*)&red[ww][s][dp + 4];
    }
    float* ab = accp + (((size_t)((b << 4) + bt)*8 + s) << 8) + dp;
    *(f32x4*)ab = a0;
    *(f32x4*)(ab + 4) = a1;
    if (tid < 8)
      sump[(((b << 4) + bt) << 3) + tid] =
          rsum[0][tid] + rsum[1][tid] + rsum[2][tid] + rsum[3][tid];
  }
}

// ---------------------------------------------------------------------------
// fuse R6: 64 blocks x 512 thr (8 waves, 2 waves/SIMD). mode1: reduce 16
// partials -> updates -> GRU -> LN -> MLP -> residual -> slots (+out).
// Always: pack next-iter q. MFMA work split: wave w owns 2 d-tiles
// (GRU/MLP2/q) or 4 col-tiles (MLP1); pack phases use 4 floats/thread.
// ---------------------------------------------------------------------------
DEV void ln_stats512(const float hpr[16][260], float stats[16][2], int tid) {
  int row = tid >> 5, seg = tid & 31;    // 512 thr = 16 rows x 32 segs x 8 el
  float s = 0.f, s2 = 0.f;
#pragma unroll
  for (int jj = 0; jj < 8; ++jj) { float v = hpr[row][seg*8 + jj]; s += v; s2 += v*v; }
  s  += __shfl_xor(s, 1);  s  += __shfl_xor(s, 2);  s  += __shfl_xor(s, 4);
  s  += __shfl_xor(s, 8);  s  += __shfl_xor(s, 16);
  s2 += __shfl_xor(s2, 1); s2 += __shfl_xor(s2, 2); s2 += __shfl_xor(s2, 4);
  s2 += __shfl_xor(s2, 8); s2 += __shfl_xor(s2, 16);
  if (seg == 0) {
    float mean = s * 0.00390625f;
    float var  = s2 * 0.00390625f - mean*mean;
    stats[row][0] = mean;
    stats[row][1] = rsqrtf(fmaxf(var, 0.f) + 1e-5f);
  }
}

__global__ __launch_bounds__(512, 2) void fuse(
    int mode, int last,
    float* __restrict__ slots,
    const float* __restrict__ accp, const float* __restrict__ sump,
    const unsigned short* __restrict__ wgru,
    const unsigned short* __restrict__ wm1,
    const unsigned short* __restrict__ wm2,
    const unsigned short* __restrict__ wq_,
    unsigned short* __restrict__ qfg,
    const float* __restrict__ gbi, const float* __restrict__ gbh,
    const float* __restrict__ lnsg, const float* __restrict__ lnsb,
    const float* __restrict__ lnfg, const float* __restrict__ lnfb,
    const float* __restrict__ mb1, const float* __restrict__ mb2,
    float* __restrict__ outp)
{
  __shared__ unsigned short uimg[4096];   // [8 dc][64][8] A-frag image (reused 3x)
  __shared__ unsigned short himg[4096];
  __shared__ unsigned short h1img[8192];  // [16 dc][64][8]
  __shared__ float hpr[16][260];
  __shared__ float stats[16][2];
  __shared__ float rowsum[8];
  int tid = threadIdx.x, w = tid >> 6, L = tid & 63;
  int m16 = L & 15, q = L >> 4;
  int b = blockIdx.x;
  for (int i = tid; i < 4096; i += 512) { uimg[i] = 0; himg[i] = 0; }
  __syncthreads();
  float hh[2][4];

  if (mode == 1) {
    if (tid < 8) {
      float s = 0.f;
      for (int p = 0; p < 16; ++p) s += sump[((b << 4) + p)*8 + tid];
      rowsum[tid] = s;
    }
    __syncthreads();
    { // reduce 16 block-partials -> updates, pack A-frag images (updates + prev)
      int s = tid >> 6, dp = (tid & 63) << 2;     // 4 floats/thread
      const float* base = accp + (((size_t)(b << 4)*8 + s) << 8) + dp;
      f32x4 a0 = (f32x4){0.f,0.f,0.f,0.f};
      for (int p = 0; p < 16; ++p)
        a0 += *(const f32x4*)(base + (size_t)p * 2048);
      float inv = 1.f / rowsum[s];
      int dc = dp >> 5, lp = s + ((dp >> 3) & 3)*16, j0 = dp & 7;  // 0 or 4
      us4 pk;
#pragma unroll
      for (int j = 0; j < 4; ++j) pk[j] = f2bf(a0[j]*inv);
      *(us4*)&uimg[(dc*64 + lp)*8 + j0] = pk;
      f32x4 h0 = *(const f32x4*)(slots + ((b << 3) + s)*256 + dp);
      us4 pk2;
#pragma unroll
      for (int j = 0; j < 4; ++j) pk2[j] = f2bf(h0[j]);
      *(us4*)&himg[(dc*64 + lp)*8 + j0] = pk2;
    }
    __syncthreads();
    // GRU MFMA: wave w owns d-tiles 2w, 2w+1; gates r/z/n col-local per d
    f32x4 aI[2][3], aH[2][3];
#pragma unroll
    for (int i = 0; i < 2; ++i)
#pragma unroll
      for (int g = 0; g < 3; ++g) { aI[i][g] = (f32x4){0.f,0.f,0.f,0.f}; aH[i][g] = (f32x4){0.f,0.f,0.f,0.f}; }
#pragma unroll
    for (int dc = 0; dc < 8; ++dc) {
      short8 au = *(const short8*)(uimg + (dc*64 + L)*8);
      short8 ah = *(const short8*)(himg + (dc*64 + L)*8);
#pragma unroll
      for (int i = 0; i < 2; ++i) {
        int dt = (w << 1) + i;
#pragma unroll
        for (int g = 0; g < 3; ++g) {
          short8 bu = *(const short8*)(wgru + (((g*16 + dt)*8 + dc)*64 + L)*8);
          aI[i][g] = mfma16(au, bu, aI[i][g]);
          short8 bh = *(const short8*)(wgru + (((48 + g*16 + dt)*8 + dc)*64 + L)*8);
          aH[i][g] = mfma16(ah, bh, aH[i][g]);
        }
      }
    }
#pragma unroll
    for (int i = 0; i < 2; ++i) {
      int d = ((w << 1) + i)*16 + m16;
      float bir = gbi[d], biz = gbi[256+d], bin = gbi[512+d];
      float bhr = gbh[d], bhz = gbh[256+d], bhn = gbh[512+d];
#pragma unroll
      for (int r = 0; r < 4; ++r) {
        int s = (q << 2) + r;
        if (s < 8) {
          float ir = aI[i][0][r] + bir, iz = aI[i][1][r] + biz, in_ = aI[i][2][r] + bin;
          float hr = aH[i][0][r] + bhr, hz = aH[i][1][r] + bhz, hn = aH[i][2][r] + bhn;
          float rg = 1.f / (1.f + __expf(-(ir + hr)));
          float zg = 1.f / (1.f + __expf(-(iz + hz)));
          float nn = tanhf(in_ + rg * hn);
          float hv = slots[((b << 3) + s)*256 + d];
          float hp = (1.f - zg)*nn + zg*hv;
          hh[i][r] = hp;
          hpr[s][d] = hp;
        } else {
          hpr[s][d] = 0.f;
        }
      }
    }
    __syncthreads();
    ln_stats512(hpr, stats, tid);
    __syncthreads();
    { // LN_ff -> A image
      int s = tid >> 6, dp = (tid & 63) << 2;
      float mean = stats[s][0], rstd = stats[s][1];
      int dc = dp >> 5, lp = s + ((dp >> 3) & 3)*16, j0 = dp & 7;
      us4 pk;
#pragma unroll
      for (int j = 0; j < 4; ++j)
        pk[j] = f2bf((hpr[s][dp+j] - mean)*rstd*lnfg[dp+j] + lnfb[dp+j]);
      *(us4*)&uimg[(dc*64 + lp)*8 + j0] = pk;
    }
    __syncthreads();
    // MLP layer 1 (relu) -> h1 A-frag image; wave w owns 4 col-tiles
    f32x4 a1[4];
#pragma unroll
    for (int c = 0; c < 4; ++c) a1[c] = (f32x4){0.f,0.f,0.f,0.f};
#pragma unroll
    for (int dc = 0; dc < 8; ++dc) {
      short8 aa = *(const short8*)(uimg + (dc*64 + L)*8);
#pragma unroll
      for (int c = 0; c < 4; ++c) {
        short8 bb = *(const short8*)(wm1 + ((((w<<2)+c)*8 + dc)*64 + L)*8);
        a1[c] = mfma16(aa, bb, a1[c]);
      }
    }
#pragma unroll
    for (int c = 0; c < 4; ++c) {
      int col = ((w << 2) + c)*16 + m16;
      float bv = mb1[col];
      int dc2 = col >> 5, lpb = ((col >> 3) & 3)*16, j = col & 7;
#pragma unroll
      for (int r = 0; r < 4; ++r) {
        int s = (q << 2) + r;
        float v = (s < 8) ? fmaxf(a1[c][r] + bv, 0.f) : 0.f;
        h1img[(dc2*64 + s + lpb)*8 + j] = f2bf(v);
      }
    }
    __syncthreads();
    // MLP layer 2 + residual; wave's col tiles == its GRU d-tiles
    f32x4 a2[2];
#pragma unroll
    for (int i = 0; i < 2; ++i) a2[i] = (f32x4){0.f,0.f,0.f,0.f};
#pragma unroll
    for (int dc2 = 0; dc2 < 16; ++dc2) {
      short8 aa = *(const short8*)(h1img + (dc2*64 + L)*8);
#pragma unroll
      for (int i = 0; i < 2; ++i) {
        short8 bb = *(const short8*)(wm2 + ((((w<<1)+i)*16 + dc2)*64 + L)*8);
        a2[i] = mfma16(aa, bb, a2[i]);
      }
    }
#pragma unroll
    for (int i = 0; i < 2; ++i) {
      int d = ((w << 1) + i)*16 + m16;
      float b2v = mb2[d];
#pragma unroll
      for (int r = 0; r < 4; ++r) {
        int s = (q << 2) + r;
        if (s < 8) {
          float o = a2[i][r] + b2v + hh[i][r];
          slots[((b << 3) + s)*256 + d] = o;
          if (last) outp[((b << 3) + s)*256 + d] = o;
          hpr[s][d] = o;
        }
      }
    }
    __syncthreads();
  } else {
    int s = tid >> 6, dp = (tid & 63) << 2;
#pragma unroll
    for (int j = 0; j < 4; ++j) {
      hpr[s][dp+j] = slots[((b << 3) + s)*256 + dp + j];
      hpr[8 + s][dp+j] = 0.f;
    }
    __syncthreads();
  }

  // q for next attention pass: LN_slots -> @q_w -> B-frag-direct global image
  ln_stats512(hpr, stats, tid);
  __syncthreads();
  {
    int s = tid >> 6, dp = (tid & 63) << 2;
    float mean = stats[s][0], rstd = stats[s][1];
    int dc = dp >> 5, lp = s + ((dp >> 3) & 3)*16, j0 = dp & 7;
    us4 pk;
#pragma unroll
    for (int j = 0; j < 4; ++j)
      pk[j] = f2bf((hpr[s][dp+j] - mean)*rstd*lnsg[dp+j] + lnsb[dp+j]);
    *(us4*)&uimg[(dc*64 + lp)*8 + j0] = pk;
  }
  __syncthreads();
  {
    f32x4 aq[2];
#pragma unroll
    for (int i = 0; i < 2; ++i) aq[i] = (f32x4){0.f,0.f,0.f,0.f};
#pragma unroll
    for (int dc = 0; dc < 8; ++dc) {
      short8 aa = *(const short8*)(uimg + (dc*64 + L)*8);
#pragma unroll
      for (int i = 0; i < 2; ++i) {
        short8 bb = *(const short8*)(wq_ + ((((w<<1)+i)*8 + dc)*64 + L)*8);
        aq[i] = mfma16(aa, bb, aq[i]);
      }
    }
    unsigned short* qb = qfg + ((size_t)b << 12);
#pragma unroll
    for (int i = 0; i < 2; ++i) {
      int col = ((w << 1) + i)*16 + m16;
      int dc = col >> 5, lpb = ((col >> 3) & 3)*16, j = col & 7;
#pragma unroll
      for (int r = 0; r < 4; ++r) {
        int s = (q << 2) + r;
        qb[(dc*64 + s + lpb)*8 + j] = (s < 8) ? f2bf(aq[i][r]) : (unsigned short)0;
      }
    }
  }
}

// ---------------------------------------------------------------------------
extern "C" void kernel_launch(void* const* d_in, const int* in_sizes, int n_in,
                              void* d_out, int out_size, void* d_ws, size_t ws_size,
                              hipStream_t stream) {
  (void)in_sizes; (void)n_in; (void)out_size;
  if (ws_size < WS_NEED) return;   // workspace guard (need ~275 MB)

  const float* inputs    = (const float*)d_in[0];
  const float* slot_init = (const float*)d_in[1];
  const float* k_w       = (const float*)d_in[2];
  const float* q_w       = (const float*)d_in[3];
  const float* v_w       = (const float*)d_in[4];
  const float* gru_wi    = (const float*)d_in[5];
  const float* gru_wh    = (const float*)d_in[6];
  const float* gru_bi    = (const float*)d_in[7];
  const float* gru_bh    = (const float*)d_in[8];
  const float* ln_in_g   = (const float*)d_in[9];
  const float* ln_in_b   = (const float*)d_in[10];
  const float* ln_s_g    = (const float*)d_in[11];
  const float* ln_s_b    = (const float*)d_in[12];
  const float* ln_f_g    = (const float*)d_in[13];
  const float* ln_f_b    = (const float*)d_in[14];
  const float* m_w1      = (const float*)d_in[15];
  const float* m_b1      = (const float*)d_in[16];
  const float* m_w2      = (const float*)d_in[17];
  const float* m_b2      = (const float*)d_in[18];

  char* ws = (char*)d_ws;
  unsigned short* kfr  = (unsigned short*)(ws + O_KF);
  unsigned short* vfr  = (unsigned short*)(ws + O_VF);
  float*          accp = (float*)(ws + O_ACC);
  float*          sump = (float*)(ws + O_SUM);
  float*          slots= (float*)(ws + O_SL);
  unsigned short* qfg  = (unsigned short*)(ws + O_QF);
  unsigned short* wkv  = (unsigned short*)(ws + O_WKV);
  unsigned short* wq_  = (unsigned short*)(ws + O_WQ);
  unsigned short* wgru = (unsigned short*)(ws + O_WGRU);
  unsigned short* wm1  = (unsigned short*)(ws + O_WM1);
  unsigned short* wm2  = (unsigned short*)(ws + O_WM2);

  prepack<<<544, 256, 0, stream>>>(k_w, q_w, v_w, gru_wi, gru_wh, m_w1, m_w2,
                                   slot_init, wkv, wq_, wgru, wm1, wm2, slots);
  gemm_kv<<<4096, 512, 0, stream>>>(inputs, ln_in_g, ln_in_b, wkv, kfr, vfr);
  fuse<<<64, 512, 0, stream>>>(0, 0, slots, accp, sump, wgru, wm1, wm2, wq_, qfg,
                               gru_bi, gru_bh, ln_s_g, ln_s_b, ln_f_g, ln_f_b,
                               m_b1, m_b2, (float*)d_out);
  for (int it = 0; it < 3; ++it) {
    attn<<<dim3(16, 64), 256, 0, stream>>>(kfr, vfr, qfg, accp, sump);
    fuse<<<64, 512, 0, stream>>>(1, (it == 2) ? 1 : 0, slots, accp, sump, wgru,
                                 wm1, wm2, wq_, qfg, gru_bi, gru_bh, ln_s_g,
                                 ln_s_b, ln_f_g, ln_f_b, m_b1, m_b2,
                                 (float*)d_out);
  }
}